// Round 6
// baseline (3749.200 us; speedup 1.0000x reference)
//
#include <hip/hip_runtime.h>
#include <hip/hip_bf16.h>

// ViT forward, MI355X. A-stationary barrier-free GEMM (full-K A tile in LDS,
// B streamed L2->VGPR, no inner barriers, 2 blocks/CU), LN fused into proj and
// FFN2 epilogues, FFN1 interleaved packed stores (+w2T k-perm), fused flash
// attention. Adaptive workspace via batch chunking.

typedef unsigned short u16;
typedef __hip_bfloat16 bf16;
typedef __bf16 bf16x8 __attribute__((ext_vector_type(8)));
typedef float f32x4 __attribute__((ext_vector_type(4)));

typedef const __attribute__((address_space(1))) void* gas_ptr;
typedef __attribute__((address_space(3))) void* las_ptr;

#define TOKENS 577
#define TPAD   640
#define DMODEL 512
#define SM_SCALE 0.08838834764831845f   /* 128^-0.5 */

static __device__ __forceinline__ u16 f2b(float v) {
    bf16 t = __float2bfloat16(v);
    return *(u16*)&t;
}

// ---------------------------------------------------------------------------
// A-stationary GEMM. Block: 64 M-rows, 512 threads = 8 waves; wave w owns
// 64 output cols of each 512-col N-chunk. A (64 x KSTAGE) staged in LDS once
// (XOR-swizzled octets: LDS[r][s] = glob octet (s&~7)|((s&7)^(r&7))), then a
// barrier-FREE main loop: B fragments stream global->VGPR (L2-hot weights)
// with depth-2 prefetch; 16 MFMA per kf.
// OUTMODE 0: plain bf16 out. 1: patch-embed (row remap, +bias+pos, f32+bf16).
// 2: LN-fused (+bias, +residual, LayerNorm, f32+bf16). 3: bias+gelu,
//    column-interleaved packed store (phys col = lr*4+n).
// ---------------------------------------------------------------------------
template<int KSTAGE, int OUTMODE>
__global__ __launch_bounds__(512)
void gemm3(const u16* __restrict__ A, int lda,
           const u16* __restrict__ Bt, int ldb,
           float* __restrict__ outf, bf16* __restrict__ outb, int ldc,
           const float* __restrict__ bias, const float* __restrict__ pos,
           const float* __restrict__ gam, const float* __restrict__ bet,
           const float* __restrict__ resf,
           int K, int N, int rows_valid)
{
    constexpr int OPR = KSTAGE / 8;        // octets per A row
    __shared__ u16 As[64 * KSTAGE];
    __shared__ float redS[8][64];
    __shared__ float redQ[8][64];
    const int tid = threadIdx.x;
    const int wid = tid >> 6;
    const int lane = tid & 63;
    const int lr = lane & 15, lg = lane >> 4;
    const long row0 = (long)blockIdx.x * 64;
    const u16* Ab = A + row0 * lda;

    auto stageA = [&](int ks) {
#pragma unroll
        for (int i = 0; i < (64 * OPR) / 512; ++i) {
            const int g = i * 512 + tid;
            const int r = g / OPR, sl = g - r * OPR;
            const int so = (sl & ~7) | ((sl & 7) ^ (r & 7));
            __builtin_amdgcn_global_load_lds(
                (gas_ptr)(Ab + (long)r * lda + ks + so * 8),
                (las_ptr)&As[g * 8], 16, 0, 0);
        }
    };

    stageA(0);
    __syncthreads();

    for (int nc = 0; nc < N; nc += 512) {
        const int cb = nc + wid * 64;
        const u16* Bp[4];
#pragma unroll
        for (int n = 0; n < 4; ++n)
            Bp[n] = Bt + (long)(cb + n * 16 + lr) * ldb + lg * 8;
        f32x4 acc[4][4] = {};

        for (int ks = 0; ks < K; ks += KSTAGE) {
            if (ks) { __syncthreads(); stageA(ks); __syncthreads(); }
            constexpr int NK = KSTAGE / 32;
            bf16x8 bb[3][4];
#pragma unroll
            for (int n = 0; n < 4; ++n) bb[0][n] = *(const bf16x8*)&Bp[n][ks];
#pragma unroll
            for (int n = 0; n < 4; ++n) bb[1][n] = *(const bf16x8*)&Bp[n][ks + 32];
#pragma unroll
            for (int kf = 0; kf < NK; ++kf) {
                if (kf + 2 < NK) {
#pragma unroll
                    for (int n = 0; n < 4; ++n)
                        bb[(kf + 2) % 3][n] = *(const bf16x8*)&Bp[n][ks + (kf + 2) * 32];
                }
                bf16x8 af[4];
#pragma unroll
                for (int m = 0; m < 4; ++m) {
                    const int r = m * 16 + lr;
                    const int o = kf * 4 + lg;
                    const int so = (o & ~7) | ((o & 7) ^ (r & 7));
                    af[m] = *(const bf16x8*)&As[r * KSTAGE + so * 8];
                }
                __builtin_amdgcn_s_setprio(1);
#pragma unroll
                for (int m = 0; m < 4; ++m)
#pragma unroll
                    for (int n = 0; n < 4; ++n)
                        acc[m][n] = __builtin_amdgcn_mfma_f32_16x16x32_bf16(
                            af[m], bb[kf % 3][n], acc[m][n], 0, 0, 0);
                __builtin_amdgcn_s_setprio(0);
            }
        }

        // ---------------- epilogues ----------------
        if constexpr (OUTMODE == 0) {
#pragma unroll
            for (int m = 0; m < 4; ++m)
#pragma unroll
                for (int j = 0; j < 4; ++j) {
                    const long r = row0 + m * 16 + lg * 4 + j;
                    if (r >= rows_valid) continue;
#pragma unroll
                    for (int n = 0; n < 4; ++n)
                        outb[r * ldc + cb + n * 16 + lr] = __float2bfloat16(acc[m][n][j]);
                }
        } else if constexpr (OUTMODE == 1) {
            float bval[4];
#pragma unroll
            for (int n = 0; n < 4; ++n) bval[n] = bias[cb + n * 16 + lr];
#pragma unroll
            for (int m = 0; m < 4; ++m)
#pragma unroll
                for (int j = 0; j < 4; ++j) {
                    const long r = row0 + m * 16 + lg * 4 + j;
                    if (r >= rows_valid) continue;
                    const int pb = (int)(r / 576), pt = (int)(r - (long)pb * 576);
                    const long orow = (long)pb * TOKENS + 1 + pt;
#pragma unroll
                    for (int n = 0; n < 4; ++n) {
                        const int c = cb + n * 16 + lr;
                        const float v = acc[m][n][j] + bval[n] + pos[(long)(1 + pt) * DMODEL + c];
                        outf[orow * ldc + c] = v;
                        outb[orow * ldc + c] = __float2bfloat16(v);
                    }
                }
        } else if constexpr (OUTMODE == 3) {
            float bval[4];
#pragma unroll
            for (int n = 0; n < 4; ++n) bval[n] = bias[cb + n * 16 + lr];
#pragma unroll
            for (int m = 0; m < 4; ++m)
#pragma unroll
                for (int j = 0; j < 4; ++j) {
                    const long r = row0 + m * 16 + lg * 4 + j;
                    if (r >= rows_valid) continue;
                    u16 pk[4];
#pragma unroll
                    for (int n = 0; n < 4; ++n) {
                        float v = acc[m][n][j] + bval[n];
                        v = 0.5f * v * (1.0f + erff(v * 0.70710678118654752f));
                        pk[n] = f2b(v);
                    }
                    *(uint2*)&outb[r * ldc + cb + lr * 4] = *(uint2*)pk;
                }
        } else {  // OUTMODE 2: +bias +residual, LayerNorm, write f32 + bf16
            float bval[4];
#pragma unroll
            for (int n = 0; n < 4; ++n) bval[n] = bias ? bias[cb + n * 16 + lr] : 0.0f;
            float ps[4][4], pq[4][4];
#pragma unroll
            for (int m = 0; m < 4; ++m)
#pragma unroll
                for (int j = 0; j < 4; ++j) {
                    const long r = row0 + m * 16 + lg * 4 + j;
                    float s = 0.f, q = 0.f;
#pragma unroll
                    for (int n = 0; n < 4; ++n) {
                        const float v = acc[m][n][j] + bval[n] + resf[r * DMODEL + cb + n * 16 + lr];
                        acc[m][n][j] = v;
                        s += v; q += v * v;
                    }
                    ps[m][j] = s; pq[m][j] = q;
                }
#pragma unroll
            for (int o = 1; o < 16; o <<= 1)
#pragma unroll
                for (int m = 0; m < 4; ++m)
#pragma unroll
                    for (int j = 0; j < 4; ++j) {
                        ps[m][j] += __shfl_xor(ps[m][j], o);
                        pq[m][j] += __shfl_xor(pq[m][j], o);
                    }
            if (lr == 0) {
#pragma unroll
                for (int m = 0; m < 4; ++m)
#pragma unroll
                    for (int j = 0; j < 4; ++j) {
                        redS[wid][m * 16 + lg * 4 + j] = ps[m][j];
                        redQ[wid][m * 16 + lg * 4 + j] = pq[m][j];
                    }
            }
            __syncthreads();
            if (tid < 64) {
                float s = 0.f, q = 0.f;
#pragma unroll
                for (int w = 0; w < 8; ++w) { s += redS[w][tid]; q += redQ[w][tid]; }
                const float mean = s * (1.f / 512.f);
                const float var = q * (1.f / 512.f) - mean * mean;
                redS[0][tid] = mean;
                redQ[0][tid] = rsqrtf(var + 1e-5f);
            }
            __syncthreads();
#pragma unroll
            for (int m = 0; m < 4; ++m)
#pragma unroll
                for (int j = 0; j < 4; ++j) {
                    const long r = row0 + m * 16 + lg * 4 + j;
                    if (r >= rows_valid) continue;
                    const int ri = m * 16 + lg * 4 + j;
                    const float mean = redS[0][ri], rs = redQ[0][ri];
#pragma unroll
                    for (int n = 0; n < 4; ++n) {
                        const int c = cb + n * 16 + lr;
                        const float o = (acc[m][n][j] - mean) * rs * gam[c] + bet[c];
                        outf[r * DMODEL + c] = o;
                        outb[r * DMODEL + c] = __float2bfloat16(o);
                    }
                }
        }
    }
}

// ---------------------------------------------------------------------------
// Fused flash attention. Grid: (5 q-tiles, NP pairs). 256 threads = 4 waves.
// qkv layout (permuted): [row][ kk*512 + h*128 + d ], row = b*577 + t (+pad).
// ---------------------------------------------------------------------------
__global__ __launch_bounds__(256, 2)
void attn_flash(const u16* __restrict__ qkv, const u16* __restrict__ vhT,
                bf16* __restrict__ ob)
{
    __shared__ u16 ldsA[128 * 128];   // K tile, then P tile
    __shared__ u16 ldsB[128 * 128];   // V^T tile [d][kv]
    const int tid = threadIdx.x;
    const int w = tid >> 6, lane = tid & 63;
    const int lr = lane & 15, lg = lane >> 4;
    const int pair = blockIdx.y;
    const int b = pair >> 2, h = pair & 3;
    const int q0 = blockIdx.x * 128;
    const long rowbase = (long)b * TOKENS;

    bf16x8 qf[2][4];
#pragma unroll
    for (int m = 0; m < 2; ++m)
#pragma unroll
        for (int kf = 0; kf < 4; ++kf) {
            const long r = rowbase + q0 + w * 32 + m * 16 + lr;
            qf[m][kf] = *(const bf16x8*)&qkv[r * 1536 + h * 128 + kf * 32 + lg * 8];
        }

    float mrun[2][4], lrun[2][4];
#pragma unroll
    for (int m = 0; m < 2; ++m)
#pragma unroll
        for (int j = 0; j < 4; ++j) { mrun[m][j] = -1e30f; lrun[m][j] = 0.f; }
    f32x4 oacc[2][8] = {};

    for (int kv0 = 0; kv0 < TPAD; kv0 += 128) {
        {
            const u16* kg = qkv + (rowbase + kv0) * 1536 + 512 + h * 128;
            const u16* vg = vhT + ((long)pair * 128) * TPAD + kv0;
#pragma unroll
            for (int p = 0; p < 8; ++p) {
                const int i = p * 16 + w * 4 + lg;
                __builtin_amdgcn_global_load_lds((gas_ptr)(kg + (long)i * 1536 + lr * 8),
                                                 (las_ptr)&ldsA[(p * 16 + w * 4) * 128], 16, 0, 0);
                __builtin_amdgcn_global_load_lds((gas_ptr)(vg + (long)i * TPAD + lr * 8),
                                                 (las_ptr)&ldsB[(p * 16 + w * 4) * 128], 16, 0, 0);
            }
        }
        __syncthreads();

        f32x4 s[2][8] = {};
#pragma unroll
        for (int kf = 0; kf < 4; ++kf) {
            bf16x8 bv[8];
#pragma unroll
            for (int n = 0; n < 8; ++n)
                bv[n] = *(const bf16x8*)&ldsA[(n * 16 + lr) * 128 + kf * 32 + lg * 8];
            __builtin_amdgcn_s_setprio(1);
#pragma unroll
            for (int m = 0; m < 2; ++m)
#pragma unroll
                for (int n = 0; n < 8; ++n)
                    s[m][n] = __builtin_amdgcn_mfma_f32_16x16x32_bf16(qf[m][kf], bv[n], s[m][n], 0, 0, 0);
            __builtin_amdgcn_s_setprio(0);
        }

        float sc[2][4];
#pragma unroll
        for (int m = 0; m < 2; ++m)
#pragma unroll
            for (int jj = 0; jj < 4; ++jj) {
                float mx = mrun[m][jj];
#pragma unroll
                for (int n = 0; n < 8; ++n) {
                    const int col = kv0 + n * 16 + lr;
                    float v = s[m][n][jj] * SM_SCALE;
                    v = (col < TOKENS) ? v : -1e30f;
                    s[m][n][jj] = v;
                    mx = fmaxf(mx, v);
                }
#pragma unroll
                for (int o = 1; o < 16; o <<= 1) mx = fmaxf(mx, __shfl_xor(mx, o));
                const float f = __expf(mrun[m][jj] - mx);
                sc[m][jj] = f;
                float sum = 0.f;
#pragma unroll
                for (int n = 0; n < 8; ++n) {
                    const float p = __expf(s[m][n][jj] - mx);
                    s[m][n][jj] = p;
                    sum += p;
                }
#pragma unroll
                for (int o = 1; o < 16; o <<= 1) sum += __shfl_xor(sum, o);
                lrun[m][jj] = lrun[m][jj] * f + sum;
                mrun[m][jj] = mx;
            }
#pragma unroll
        for (int m = 0; m < 2; ++m)
#pragma unroll
            for (int n = 0; n < 8; ++n)
#pragma unroll
                for (int jj = 0; jj < 4; ++jj) oacc[m][n][jj] *= sc[m][jj];

        __syncthreads();
#pragma unroll
        for (int m = 0; m < 2; ++m)
#pragma unroll
            for (int n = 0; n < 8; ++n)
#pragma unroll
                for (int jj = 0; jj < 4; ++jj)
                    ldsA[(w * 32 + m * 16 + lg * 4 + jj) * 128 + n * 16 + lr] = f2b(s[m][n][jj]);
        __syncthreads();

#pragma unroll
        for (int kf = 0; kf < 4; ++kf) {
            bf16x8 pa[2];
#pragma unroll
            for (int m = 0; m < 2; ++m)
                pa[m] = *(const bf16x8*)&ldsA[(w * 32 + m * 16 + lr) * 128 + kf * 32 + lg * 8];
            __builtin_amdgcn_s_setprio(1);
#pragma unroll
            for (int n = 0; n < 8; ++n) {
                const bf16x8 vb = *(const bf16x8*)&ldsB[(n * 16 + lr) * 128 + kf * 32 + lg * 8];
#pragma unroll
                for (int m = 0; m < 2; ++m)
                    oacc[m][n] = __builtin_amdgcn_mfma_f32_16x16x32_bf16(pa[m], vb, oacc[m][n], 0, 0, 0);
            }
            __builtin_amdgcn_s_setprio(0);
        }
        __syncthreads();
    }

#pragma unroll
    for (int m = 0; m < 2; ++m)
#pragma unroll
        for (int jj = 0; jj < 4; ++jj) {
            const float inv = 1.f / lrun[m][jj];
            const int q = q0 + w * 32 + m * 16 + lg * 4 + jj;
            if (q >= TOKENS) continue;
#pragma unroll
            for (int n = 0; n < 8; ++n)
                ob[(rowbase + q) * DMODEL + h * 128 + n * 16 + lr] =
                    __float2bfloat16(oacc[m][n][jj] * inv);
        }
}

// ---------------------------------------------------------------------------
// Weight transpose + f32->bf16:  WT[n][k] = bf16(W[k][n]).
// MODE 0: plain. MODE 1: qkv col perm (n' = kk*512 + h*128 + d).
// MODE 2: k-perm for w2T matching FFN1's interleaved phys cols:
//         store at k-pos q=(s&15)*4+(s>>4) within each 64-block (s = src k%64).
// ---------------------------------------------------------------------------
template<int MODE>
__global__ __launch_bounds__(256)
void wtrans(const float* __restrict__ W, bf16* __restrict__ WT, int K, int N)
{
    __shared__ float tile[32][33];
    const int n0 = blockIdx.x * 32, k0 = blockIdx.y * 32;
    const int tx = threadIdx.x & 31, ty = threadIdx.x >> 5;
#pragma unroll
    for (int i = 0; i < 4; ++i)
        tile[ty + i * 8][tx] = W[(long)(k0 + ty + i * 8) * N + n0 + tx];
    __syncthreads();
#pragma unroll
    for (int i = 0; i < 4; ++i) {
        int n = n0 + ty + i * 8;
        if constexpr (MODE == 1) {
            const int d = n / 12, r = n % 12;
            n = (r >> 2) * 512 + (r & 3) * 128 + d;
        }
        int kk = k0 + tx;
        if constexpr (MODE == 2) {
            const int s = kk & 63;
            kk = (kk & ~63) | (((s & 15) << 2) | (s >> 4));
        }
        WT[(long)n * K + kk] = __float2bfloat16(tile[tx][ty + i * 8]);
    }
}

// ---------------------------------------------------------------------------
// Patch gather: img (Bc,3,384,384) -> pat[b*576 + x*24+y][p1*48 + p2*3 + c] bf16
// ---------------------------------------------------------------------------
__global__ __launch_bounds__(64)
void patch_gather(const float* __restrict__ img, bf16* __restrict__ pat)
{
    const int bid = blockIdx.x;
    const int x  = bid % 24;
    const int p1 = (bid / 24) % 16;
    const int b  = bid / (24 * 16);
    __shared__ bf16 lds[24][48];
    const int lane = threadIdx.x;
    const int h = p1 * 24 + x;
    for (int c = 0; c < 3; ++c) {
        const float* row = img + ((long)(b * 3 + c) * 384 + h) * 384;
#pragma unroll
        for (int i = 0; i < 6; ++i) {
            const int wpix = lane + i * 64;
            const float v = row[wpix];
            const int y = wpix % 24, p2 = wpix / 24;
            lds[y][p2 * 3 + c] = __float2bfloat16(v);
        }
    }
    __syncthreads();
    for (int idx = lane; idx < 24 * 48; idx += 64) {
        const int y = idx / 48, j = idx % 48;
        pat[(long)(b * 576 + x * 24 + y) * 768 + p1 * 48 + j] = lds[y][j];
    }
}

// cls token row
__global__ __launch_bounds__(256)
void clsfill(const float* __restrict__ cls, const float* __restrict__ pos,
             float* __restrict__ tokf, bf16* __restrict__ xb)
{
    const int i = blockIdx.x * 256 + threadIdx.x;
    const int b = i >> 9, d = i & 511;
    const float v = cls[d] + pos[d];
    tokf[(long)b * TOKENS * DMODEL + d] = v;
    xb[(long)b * TOKENS * DMODEL + d] = __float2bfloat16(v);
}

// ---------------------------------------------------------------------------
// v (qkv permuted col 1024 + h*128 + d) -> vhT[(pair)*128 + d][t], t>=577 -> 0
// ---------------------------------------------------------------------------
__global__ __launch_bounds__(256)
void repack_v(const u16* __restrict__ qkv, u16* __restrict__ vhT)
{
    __shared__ u16 lds[64][136];
    const int bid = blockIdx.x;               // (pair, tt)
    const int tt = bid % 10, pair = bid / 10;
    const int b = pair >> 2, h = pair & 3;
    const int tid = threadIdx.x;
    const int tl = tid >> 2, seg = tid & 3;
    const long row = (long)b * TOKENS + tt * 64 + tl;
    const u16* src = qkv + row * 1536 + 1024 + h * 128 + seg * 32;
#pragma unroll
    for (int u = 0; u < 4; ++u)
        *(uint4*)&lds[tl][seg * 32 + u * 8] = *(const uint4*)&src[u * 8];
    __syncthreads();
    const int d = tid >> 1, th = (tid & 1) * 32;
    u16* dst = vhT + ((long)pair * 128 + d) * TPAD + tt * 64 + th;
#pragma unroll
    for (int blk = 0; blk < 4; ++blk) {
        uint4 pk; u16* pp = (u16*)&pk;
#pragma unroll
        for (int j = 0; j < 8; ++j) {
            const int t = tt * 64 + th + blk * 8 + j;
            pp[j] = (t < TOKENS) ? lds[th + blk * 8 + j][d] : (u16)0;
        }
        *(uint4*)&dst[blk * 8] = pk;
    }
}

// Head: out[b][c] = tok[b*577][:] . Whead[:,c] + bhead[c]
__global__ __launch_bounds__(64)
void head_k(const float* __restrict__ tokf, const float* __restrict__ Wh,
            const float* __restrict__ bh, float* __restrict__ out)
{
    const int b = blockIdx.x;
    const int lane = threadIdx.x;
    const float* x = tokf + (long)b * TOKENS * DMODEL;
    float acc[10] = {};
#pragma unroll
    for (int i = 0; i < 8; ++i) {
        const int d = lane + i * 64;
        const float xv = x[d];
        const float* wr = Wh + (long)d * 10;
#pragma unroll
        for (int c = 0; c < 10; ++c) acc[c] += xv * wr[c];
    }
#pragma unroll
    for (int c = 0; c < 10; ++c)
#pragma unroll
        for (int o = 32; o; o >>= 1) acc[c] += __shfl_xor(acc[c], o);
    if (lane == 0) {
#pragma unroll
        for (int c = 0; c < 10; ++c) out[b * 10 + c] = acc[c] + bh[c];
    }
}

// ---------------------------------------------------------------------------
extern "C" void kernel_launch(void* const* d_in, const int* in_sizes, int n_in,
                              void* d_out, int out_size, void* d_ws, size_t ws_size,
                              hipStream_t stream)
{
    (void)in_sizes; (void)n_in; (void)out_size;
    const float* img    = (const float*)d_in[0];
    const float* Wpatch = (const float*)d_in[1];
    const float* bpatch = (const float*)d_in[2];
    const float* clstk  = (const float*)d_in[3];
    const float* pos    = (const float*)d_in[4];
    const float* Wqkv   = (const float*)d_in[5];
    const float* W0     = (const float*)d_in[6];
    const float* g1     = (const float*)d_in[7];
    const float* b1     = (const float*)d_in[8];
    const float* g2     = (const float*)d_in[9];
    const float* b2     = (const float*)d_in[10];
    const float* W1     = (const float*)d_in[11];
    const float* bb1    = (const float*)d_in[12];
    const float* W2     = (const float*)d_in[13];
    const float* bb2    = (const float*)d_in[14];
    const float* Whead  = (const float*)d_in[15];
    const float* bhead  = (const float*)d_in[16];

    // ---- pick the largest batch chunk that fits ws (M padded to 64) ----
    static const int cand[6] = {32, 16, 8, 4, 2, 1};
    int Bc = 0;
    size_t o_tokf=0, o_xb=0, o_R1=0, o_vh=0, o_ob=0, o_wp=0, o_wr=0;
    for (int ci = 0; ci < 6; ++ci) {
        const int bc = cand[ci];
        const long Mrows = (long)bc * TOKENS;
        const long Mpad  = ((Mrows + 63) / 64) * 64;
        size_t off = 0;
        auto take = [&](size_t sz) { size_t o = off; off += (sz + 255) & ~(size_t)255; return o; };
        size_t t_tokf = take((size_t)Mpad * 512 * 4);
        size_t t_xb   = take((size_t)Mpad * 512 * 2);
        size_t t_R1   = take((size_t)Mpad * 2048 * 2);          // pat | qkv | h1b
        size_t t_vh   = take((size_t)bc * 4 * TPAD * 128 * 2);  // vhT
        size_t t_ob   = take((size_t)Mpad * 512 * 2);
        size_t t_wp   = take((size_t)512 * 768 * 2);
        size_t t_wr   = take((size_t)3145728 * 2);              // rotating layer weights
        if (off <= ws_size) {
            Bc = bc;
            o_tokf=t_tokf; o_xb=t_xb; o_R1=t_R1; o_vh=t_vh; o_ob=t_ob; o_wp=t_wp; o_wr=t_wr;
            break;
        }
    }
    if (Bc == 0) return;

    const long Mrows = (long)Bc * TOKENS;
    const long Mpad  = ((Mrows + 63) / 64) * 64;
    const int  NP    = Bc * 4;
    const int  nblk  = (int)(Mpad / 64);
    const int  nblkp = (int)(((long)Bc * 576 + 63) / 64);

    char* base = (char*)d_ws;
    float* tokf = (float*)(base + o_tokf);
    bf16*  xb   = (bf16*)(base + o_xb);
    char*  R1   = base + o_R1;
    u16*   vhT  = (u16*)(base + o_vh);
    bf16*  ob   = (bf16*)(base + o_ob);
    bf16*  wpT  = (bf16*)(base + o_wp);
    bf16*  wqkvT = (bf16*)(base + o_wr);
    bf16*  w0T   = wqkvT + 1536 * 512;
    bf16*  w1T   = w0T   + 512 * 512;
    bf16*  w2T   = w1T   + 2048 * 512;

    u16*  qkvb = (u16*)R1;
    bf16* pat  = (bf16*)R1;
    u16*  h1b  = (u16*)R1;

    wtrans<0><<<dim3(512 / 32, 768 / 32), 256, 0, stream>>>(Wpatch, wpT, 768, 512);

    const int nchunks = 32 / Bc;
    for (int ch = 0; ch < nchunks; ++ch) {
        const float* img_c = img + (long)ch * Bc * 3 * 384 * 384;

        // embed
        hipMemsetAsync(xb, 0, (size_t)Mpad * 512 * 2, stream);   // pad rows -> exact 0
        clsfill<<<Bc * 2, 256, 0, stream>>>(clstk, pos, tokf, xb);
        patch_gather<<<Bc * 16 * 24, 64, 0, stream>>>(img_c, pat);
        gemm3<768, 1><<<nblkp, 512, 0, stream>>>(
            (const u16*)pat, 768, (const u16*)wpT, 768,
            tokf, xb, 512, bpatch, pos, nullptr, nullptr, nullptr,
            768, 512, Bc * 576);

        for (int l = 0; l < 6; ++l) {
            // rotate this layer's weights to bf16 N x K
            wtrans<1><<<dim3(1536 / 32, 512 / 32), 256, 0, stream>>>(
                Wqkv + (long)l * 512 * 1536, wqkvT, 512, 1536);
            wtrans<0><<<dim3(512 / 32, 512 / 32), 256, 0, stream>>>(
                W0 + (long)l * 512 * 512, w0T, 512, 512);
            wtrans<0><<<dim3(2048 / 32, 512 / 32), 256, 0, stream>>>(
                W1 + (long)l * 512 * 2048, w1T, 512, 2048);
            wtrans<2><<<dim3(512 / 32, 2048 / 32), 256, 0, stream>>>(
                W2 + (long)l * 2048 * 512, w2T, 2048, 512);

            // qkv = x @ Wqkv  (cols: kk*512 + h*128 + d)
            gemm3<512, 0><<<nblk, 512, 0, stream>>>(
                (const u16*)xb, 512, (const u16*)wqkvT, 512,
                nullptr, (bf16*)qkvb, 1536, nullptr, nullptr, nullptr, nullptr, nullptr,
                512, 1536, (int)Mrows);

            repack_v<<<NP * 10, 256, 0, stream>>>(qkvb, vhT);
            attn_flash<<<dim3(5, NP), 256, 0, stream>>>(qkvb, vhT, ob);

            // proj + residual + LN1 -> tokf, xb
            gemm3<512, 2><<<nblk, 512, 0, stream>>>(
                (const u16*)ob, 512, (const u16*)w0T, 512,
                tokf, xb, 512, nullptr, nullptr, g1 + l * 512, b1 + l * 512, tokf,
                512, 512, (int)Mrows);

            // h1 = gelu(y @ W1 + bb1), interleaved phys cols
            gemm3<512, 3><<<nblk, 512, 0, stream>>>(
                (const u16*)xb, 512, (const u16*)w1T, 512,
                nullptr, (bf16*)h1b, 2048, bb1 + l * 2048, nullptr, nullptr, nullptr, nullptr,
                512, 2048, (int)Mrows);

            // x = LN(h1 @ W2 + bb2 + y) -> tokf, xb   (w2T k-permuted to match)
            gemm3<512, 2><<<nblk, 512, 0, stream>>>(
                (const u16*)h1b, 2048, (const u16*)w2T, 2048,
                tokf, xb, 512, bb2 + l * 512, nullptr, g2 + l * 512, b2 + l * 512, tokf,
                2048, 512, (int)Mrows);
        }

        head_k<<<Bc, 64, 0, stream>>>(tokf, Whead, bhead, (float*)d_out + (long)ch * Bc * 10);
    }
}